// Round 13
// baseline (291.148 us; speedup 1.0000x reference)
//
#include <hip/hip_runtime.h>
#include <math.h>

#define T_LEN 4096
#define D_MODEL 1280
#define H_NUM 16
#define HD 80
#define HALF 40
#define N_QKV (3*D_MODEL)

typedef short short8 __attribute__((ext_vector_type(8)));
typedef short short4v __attribute__((ext_vector_type(4)));
typedef float f32x4 __attribute__((ext_vector_type(4)));
typedef float f32x16 __attribute__((ext_vector_type(16)));
typedef float float4v __attribute__((ext_vector_type(4)));
typedef unsigned int uint4v __attribute__((ext_vector_type(4)));
typedef unsigned short ushort_t;

static __device__ __forceinline__ unsigned short f2bf(float f) {
    unsigned int u = __builtin_bit_cast(unsigned int, f);
    unsigned int r = (u + 0x7FFFu + ((u >> 16) & 1u)) >> 16;
    return (unsigned short)r;
}
static __device__ __forceinline__ float bf2f(unsigned short u) {
    return __builtin_bit_cast(float, (unsigned int)u << 16);
}

#define GLOAD16(gp, lp) \
    __builtin_amdgcn_global_load_lds((const __attribute__((address_space(1))) void*)(gp), \
                                     (__attribute__((address_space(3))) void*)(lp), 16, 0, 0)

// ---------------- rope tables ----------------
__global__ void rope_table(const float* __restrict__ rope,
                           float* __restrict__ cs, float* __restrict__ sn)
{
    int i = blockIdx.x * 256 + threadIdx.x;
    if (i < T_LEN * HALF) {
        float a = rope[i];
        cs[i] = cosf(a);
        sn[i] = sinf(a);
    }
}

// ---------------- fp32 -> bf16 elementwise (n % 1024 == 0) ----------------
__global__ __launch_bounds__(256) void cvt_bf16(const float* __restrict__ in,
                                                ushort_t* __restrict__ out)
{
    int i = (blockIdx.x * 256 + threadIdx.x) * 4;
    float4v v = *(const float4v*)&in[i];
    short4v o;
    o[0] = (short)f2bf(v[0]); o[1] = (short)f2bf(v[1]);
    o[2] = (short)f2bf(v[2]); o[3] = (short)f2bf(v[3]);
    *(short4v*)&out[i] = o;
}

// ---------------- fp32 [R][C] -> bf16 [C][R] transpose ----------------
__global__ __launch_bounds__(256) void transpose_cvt(const float* __restrict__ in,
                                                     ushort_t* __restrict__ out,
                                                     int R, int C)
{
    __shared__ float tile[64][65];
    int r0 = blockIdx.y * 64, c0 = blockIdx.x * 64;
    int tid = threadIdx.x;
    for (int i = tid; i < 4096; i += 256) {
        int r = i >> 6, c = i & 63;
        tile[r][c] = in[(size_t)(r0 + r) * C + c0 + c];
    }
    __syncthreads();
    for (int i = tid; i < 4096; i += 256) {
        int r = i >> 6, c = i & 63;
        out[(size_t)(c0 + r) * R + r0 + c] = f2bf(tile[c][r]);
    }
}

// ---------------- GEMM1 (bf16 MFMA, m97 structure): qkv = x @ Wqkv + b ----------------
__global__ __launch_bounds__(256) void gemm_qkv_mfma(const ushort_t* __restrict__ xbf,
                                                     const ushort_t* __restrict__ Wt,
                                                     const float* __restrict__ bias,
                                                     ushort_t* __restrict__ qraw,
                                                     ushort_t* __restrict__ kraw,
                                                     ushort_t* __restrict__ vt)
{
    __shared__ ushort_t As[128 * 32];
    __shared__ ushort_t Bs[128 * 32];
    const int tid = threadIdx.x;
    const int wave = tid >> 6, lane = tid & 63;
    const int g = lane >> 4, c = lane & 15;
    const int wr = wave >> 1, wc = wave & 1;
    const int m0 = blockIdx.y * 128, n0 = blockIdx.x * 128;
    const int K = D_MODEL;

    f32x4 acc[4][4];
    #pragma unroll
    for (int i = 0; i < 4; ++i)
        #pragma unroll
        for (int j = 0; j < 4; ++j) acc[i][j] = (f32x4)(0.f);

    for (int k0 = 0; k0 < K; k0 += 32) {
        #pragma unroll
        for (int q = 0; q < 2; ++q) {
            int j = wave * 128 + q * 64 + lane;
            int row = j >> 2, col8 = (j & 3) * 8;
            GLOAD16(xbf + (size_t)(m0 + row) * K + k0 + col8, &As[(wave * 2 + q) * 512]);
            GLOAD16(Wt  + (size_t)(n0 + row) * K + k0 + col8, &Bs[(wave * 2 + q) * 512]);
        }
        __syncthreads();

        short8 a[4], b[4];
        #pragma unroll
        for (int mi = 0; mi < 4; ++mi)
            a[mi] = *(const short8*)&As[(wr * 64 + mi * 16 + c) * 32 + g * 8];
        #pragma unroll
        for (int ni = 0; ni < 4; ++ni)
            b[ni] = *(const short8*)&Bs[(wc * 64 + ni * 16 + c) * 32 + g * 8];
        #pragma unroll
        for (int mi = 0; mi < 4; ++mi)
            #pragma unroll
            for (int ni = 0; ni < 4; ++ni)
                acc[mi][ni] = __builtin_amdgcn_mfma_f32_16x16x32_bf16(a[mi], b[ni], acc[mi][ni], 0, 0, 0);
        __syncthreads();
    }

    const int sel = n0 / D_MODEL;
    #pragma unroll
    for (int mi = 0; mi < 4; ++mi) {
        int tbase = m0 + wr * 64 + mi * 16 + 4 * g;
        #pragma unroll
        for (int ni = 0; ni < 4; ++ni) {
            int n = n0 + wc * 64 + ni * 16 + c;
            float bv = bias[n];
            int rem = n - sel * D_MODEL;
            int h = rem / HD, d = rem % HD;
            if (sel < 2) {
                ushort_t* dst = sel ? kraw : qraw;
                #pragma unroll
                for (int r = 0; r < 4; ++r)
                    dst[((size_t)h * T_LEN + tbase + r) * HD + d] = f2bf(acc[mi][ni][r] + bv);
            } else {
                short4v o;
                #pragma unroll
                for (int r = 0; r < 4; ++r) o[r] = (short)f2bf(acc[mi][ni][r] + bv);
                *(short4v*)&vt[((size_t)h * HD + d) * T_LEN + tbase] = o;
            }
        }
    }
}

// ---------------- rope on raw bf16 q,k; q gets scale*log2e folded in ----------------
__global__ __launch_bounds__(256) void qk_prep(const ushort_t* __restrict__ qraw,
                                               const ushort_t* __restrict__ kraw,
                                               const float* __restrict__ cs,
                                               const float* __restrict__ sn,
                                               ushort_t* __restrict__ qbf,
                                               ushort_t* __restrict__ kbf)
{
    const float SC = 0.16129842f;  // (1/sqrt(80)) * log2(e)
    int idx = blockIdx.x * 256 + threadIdx.x;
    int d = idx % HALF;
    int t = (idx / HALF) % T_LEN;
    int h = idx / (HALF * T_LEN);
    float c = cs[t * HALF + d], s = sn[t * HALF + d];
    size_t base = ((size_t)h * T_LEN + t) * HD;
    float qr = bf2f(qraw[base + d]), qi = bf2f(qraw[base + d + HALF]);
    qbf[base + d]        = f2bf((qr * c - qi * s) * SC);
    qbf[base + d + HALF] = f2bf((qr * s + qi * c) * SC);
    float kr = bf2f(kraw[base + d]), ki = bf2f(kraw[base + d + HALF]);
    kbf[base + d]        = f2bf(kr * c - ki * s);
    kbf[base + d + HALF] = f2bf(kr * s + ki * c);
}

// ---------------- Flash attention: 32x32x16 MFMA, dbuf, KV-SPLIT across blocks ----------
// Grid 1024 = 16 heads x 32 q-tiles x 2 kv-halves; 4 waves/block, 32 q-rows/wave.
// Inner loop = r10 structure (best measured, 166us): prefetch at top, store at end,
// one __syncthreads per iter, 32 iters over this block's kv half-range.
// Occupancy: LDS 50KB, VGPR ~138 -> 3 blocks/CU = 12 waves/CU (was grid-capped at 8).
// Epilogue: partial O normalized by own l (bf16) + LSE (m+log2 l, fp32) to workspace;
// merge_halves combines (exact flash 2-way merge).
// Swapped S^T = mfma(A=K, B=Q): lane holds S[kv=32*tau+crow(reg,hi)][q=ln],
//   crow(reg,hi) = (reg&3)+8*(reg>>2)+4*hi. PV A-frag via cvt_pk + permlane32_swap
//   pairs (X0,X2),(X1,X3),(X4,X6),(X5,X7)  [direction verified r7->r8].
__global__ __launch_bounds__(256) void flash_mfma(const ushort_t* __restrict__ qbf,
                                                  const ushort_t* __restrict__ kbf,
                                                  const ushort_t* __restrict__ vt,
                                                  ushort_t* __restrict__ po0,
                                                  ushort_t* __restrict__ po1,
                                                  float* __restrict__ lse_g)
{
    // XCD swizzle (T1): XCD j = bid&7 serves heads {2j,2j+1}; kvh is the fastest bit
    // so paired kv-half blocks co-locate on one XCD (same head -> L2 reuse of q).
    const int bid = blockIdx.x;               // 1024 blocks
    const int h   = 2 * (bid & 7) + ((bid >> 3) >> 6);
    const int rem = (bid >> 3) & 63;
    const int kvh = rem & 1;
    const int q0  = (rem >> 1) * 128;
    const int kvbase = kvh * 32;              // 32 kv-tiles of 64 per half
    const int tid = threadIdx.x;
    const int wq = tid >> 6;
    const int lane = tid & 63;
    const int hi = lane >> 5;
    const int ln = lane & 31;

    // Each buffer: Ks 64x88 at [0], Vs 96x72 at [5632]; buffer = 12544 ushorts.
    __shared__ ushort_t lds[2][12544];

    #pragma unroll
    for (int b = 0; b < 2; ++b)
        for (int i = tid; i < 16 * 72; i += 256)
            lds[b][5632 + (80 + i / 72) * 72 + (i % 72)] = 0;

    int goff[5], loff[5]; bool isK[5];
    #pragma unroll
    for (int u = 0; u < 5; ++u) {
        int j = tid + u * 256;
        if (j < 640) {
            int r = j / 10, cc = (j % 10) * 8;
            goff[u] = r * HD + cc; loff[u] = r * 88 + cc; isK[u] = true;
        } else {
            int jj = j - 640;
            int r = jj >> 3, cc = (jj & 7) * 8;
            goff[u] = r * T_LEN + cc; loff[u] = 5632 + r * 72 + cc; isK[u] = false;
        }
    }
    const ushort_t* gK = kbf + (size_t)h * T_LEN * HD;
    const ushort_t* gV = vt + (size_t)h * HD * T_LEN;

    short8 qf[5];
    {
        const ushort_t* qp = qbf + ((size_t)h * T_LEN + q0 + wq * 32 + ln) * HD + 8 * hi;
        #pragma unroll
        for (int ch = 0; ch < 5; ++ch) qf[ch] = *(const short8*)(qp + ch * 16);
    }

    f32x16 oacc[3];
    #pragma unroll
    for (int ft = 0; ft < 3; ++ft) oacc[ft] = (f32x16)(0.f);
    float m_run = -1e30f, l_run = 0.f;

    short8 pf[5];
    auto load_tile = [&](int ktn) {             // ktn is a GLOBAL tile index
        const ushort_t* bK = gK + ktn * 64 * HD;
        const ushort_t* bV = gV + ktn * 64;
        #pragma unroll
        for (int u = 0; u < 5; ++u)
            pf[u] = *(const short8*)((isK[u] ? bK : bV) + goff[u]);
    };
    auto store_tile = [&](ushort_t* base) {
        #pragma unroll
        for (int u = 0; u < 5; ++u)
            *(short8*)(base + loff[u]) = pf[u];
    };

    load_tile(kvbase);
    store_tile(&lds[0][0]);
    __syncthreads();

    for (int kt = 0; kt < 32; ++kt) {
        ushort_t* cur = &lds[kt & 1][0];
        ushort_t* nxt = &lds[(kt & 1) ^ 1][0];
        load_tile(kvbase + (kt < 31 ? kt + 1 : kt));    // prefetch lands during compute

        f32x16 st0 = (f32x16)(0.f), st1 = (f32x16)(0.f);
        #pragma unroll
        for (int ch = 0; ch < 5; ++ch) {
            short8 a0 = *(const short8*)(cur + ln * 88 + ch * 16 + 8 * hi);
            st0 = __builtin_amdgcn_mfma_f32_32x32x16_bf16(a0, qf[ch], st0, 0, 0, 0);
        }
        #pragma unroll
        for (int ch = 0; ch < 5; ++ch) {
            short8 a1 = *(const short8*)(cur + (32 + ln) * 88 + ch * 16 + 8 * hi);
            st1 = __builtin_amdgcn_mfma_f32_32x32x16_bf16(a1, qf[ch], st1, 0, 0, 0);
        }

        // row max: 32 in-lane + cross-half combine
        float mx = st0[0];
        #pragma unroll
        for (int i = 1; i < 16; ++i) mx = fmaxf(mx, st0[i]);
        #pragma unroll
        for (int i = 0; i < 16; ++i) mx = fmaxf(mx, st1[i]);
        mx = fmaxf(mx, __shfl_xor(mx, 32));

        // defer-max (exact): rescale only when max grew > 11 log2-units
        float al = 1.f;
        if (!__all(mx - m_run <= 11.0f)) {
            float m_new = fmaxf(m_run, mx);
            al = __builtin_amdgcn_exp2f(m_run - m_new);
            m_run = m_new;
            #pragma unroll
            for (int reg = 0; reg < 16; ++reg) {
                float alq = __shfl(al, (reg & 3) + 8 * (reg >> 2) + 4 * hi);
                oacc[0][reg] *= alq; oacc[1][reg] *= alq; oacc[2][reg] *= alq;
            }
        }

        float ps = 0.f;
        #pragma unroll
        for (int i = 0; i < 16; ++i) { st0[i] = __builtin_amdgcn_exp2f(st0[i] - m_run); ps += st0[i]; }
        #pragma unroll
        for (int i = 0; i < 16; ++i) { st1[i] = __builtin_amdgcn_exp2f(st1[i] - m_run); ps += st1[i]; }
        ps += __shfl_xor(ps, 32);
        l_run = l_run * al + ps;

        // P -> bf16 A-frags fully in-register (T12)
        unsigned int X[8], Y[8];
        #pragma unroll
        for (int k = 0; k < 8; ++k) {
            asm("v_cvt_pk_bf16_f32 %0, %1, %2" : "=v"(X[k]) : "v"(st0[2 * k]), "v"(st0[2 * k + 1]));
            asm("v_cvt_pk_bf16_f32 %0, %1, %2" : "=v"(Y[k]) : "v"(st1[2 * k]), "v"(st1[2 * k + 1]));
        }
        asm volatile("v_permlane32_swap_b32 %0, %1" : "+v"(X[0]), "+v"(X[2]));
        asm volatile("v_permlane32_swap_b32 %0, %1" : "+v"(X[1]), "+v"(X[3]));
        asm volatile("v_permlane32_swap_b32 %0, %1" : "+v"(X[4]), "+v"(X[6]));
        asm volatile("v_permlane32_swap_b32 %0, %1" : "+v"(X[5]), "+v"(X[7]));
        asm volatile("v_permlane32_swap_b32 %0, %1" : "+v"(Y[0]), "+v"(Y[2]));
        asm volatile("v_permlane32_swap_b32 %0, %1" : "+v"(Y[1]), "+v"(Y[3]));
        asm volatile("v_permlane32_swap_b32 %0, %1" : "+v"(Y[4]), "+v"(Y[6]));
        asm volatile("v_permlane32_swap_b32 %0, %1" : "+v"(Y[5]), "+v"(Y[7]));

        short8 pfrag[4];
        {
            uint4v u0 = {X[0], X[1], X[2], X[3]};
            uint4v u1 = {X[4], X[5], X[6], X[7]};
            uint4v u2 = {Y[0], Y[1], Y[2], Y[3]};
            uint4v u3 = {Y[4], Y[5], Y[6], Y[7]};
            pfrag[0] = __builtin_bit_cast(short8, u0);
            pfrag[1] = __builtin_bit_cast(short8, u1);
            pfrag[2] = __builtin_bit_cast(short8, u2);
            pfrag[3] = __builtin_bit_cast(short8, u3);
        }

        // O += P V
        #pragma unroll
        for (int ch = 0; ch < 4; ++ch) {
            #pragma unroll
            for (int ft = 0; ft < 3; ++ft) {
                short8 b = *(const short8*)(cur + 5632 + (ft * 32 + ln) * 72 + ch * 16 + 8 * hi);
                oacc[ft] = __builtin_amdgcn_mfma_f32_32x32x16_bf16(pfrag[ch], b, oacc[ft], 0, 0, 0);
            }
        }

        store_tile(nxt);
        __syncthreads();
    }

    // epilogue: partial out = O/l (bf16) + lse = m + log2(l) (fp32)
    ushort_t* po = kvh ? po1 : po0;
    float linv = 1.0f / l_run;
    float lse = m_run + __log2f(l_run);
    if (hi == 0)
        lse_g[(size_t)kvh * (H_NUM * T_LEN) + h * T_LEN + q0 + wq * 32 + ln] = lse;
    #pragma unroll
    for (int reg = 0; reg < 16; ++reg) {
        int q = (reg & 3) + 8 * (reg >> 2) + 4 * hi;
        float liq = __shfl(linv, q);
        size_t rb = (size_t)(q0 + wq * 32 + q) * D_MODEL + h * HD;
        po[rb + ln]      = f2bf(oacc[0][reg] * liq);
        po[rb + 32 + ln] = f2bf(oacc[1][reg] * liq);
        if (ln < 16)
            po[rb + 64 + ln] = f2bf(oacc[2][reg] * liq);
    }
}

// ---------------- merge the two kv-half partials (exact flash combine) ----------------
__global__ __launch_bounds__(256) void merge_halves(const ushort_t* __restrict__ po0,
                                                    const ushort_t* __restrict__ po1,
                                                    const float* __restrict__ lse_g,
                                                    ushort_t* __restrict__ outb)
{
    int i = (blockIdx.x * 256 + threadIdx.x) * 8;   // 5,242,880 elems / 8 -> grid 2560
    int t = i / D_MODEL, c = i % D_MODEL;
    int h = c / HD;
    float l0 = lse_g[h * T_LEN + t];
    float l1 = lse_g[H_NUM * T_LEN + h * T_LEN + t];
    float m = fmaxf(l0, l1);
    float w0 = __builtin_amdgcn_exp2f(l0 - m);
    float w1 = __builtin_amdgcn_exp2f(l1 - m);
    float inv = 1.0f / (w0 + w1);
    w0 *= inv; w1 *= inv;
    short8 a = *(const short8*)(po0 + i);
    short8 b = *(const short8*)(po1 + i);
    short8 o;
    #pragma unroll
    for (int j = 0; j < 8; ++j)
        o[j] = (short)f2bf(bf2f((unsigned short)a[j]) * w0 + bf2f((unsigned short)b[j]) * w1);
    *(short8*)(outb + i) = o;
}

// ---------------- GEMM2 (bf16 MFMA): out = attn @ Wo + bo, fp32 out ----------------
__global__ __launch_bounds__(256) void gemm_out_mfma(const ushort_t* __restrict__ Abf,
                                                     const ushort_t* __restrict__ Bt,
                                                     const float* __restrict__ bias,
                                                     float* __restrict__ C)
{
    __shared__ ushort_t As[128 * 32];
    __shared__ ushort_t Bs[128 * 32];
    const int tid = threadIdx.x;
    const int wave = tid >> 6, lane = tid & 63;
    const int g = lane >> 4, c = lane & 15;
    const int wr = wave >> 1, wc = wave & 1;
    const int m0 = blockIdx.y * 128, n0 = blockIdx.x * 128;
    const int K = D_MODEL;

    f32x4 acc[4][4];
    #pragma unroll
    for (int i = 0; i < 4; ++i)
        #pragma unroll
        for (int j = 0; j < 4; ++j) acc[i][j] = (f32x4)(0.f);

    for (int k0 = 0; k0 < K; k0 += 32) {
        #pragma unroll
        for (int q = 0; q < 2; ++q) {
            int j = wave * 128 + q * 64 + lane;
            int row = j >> 2, col8 = (j & 3) * 8;
            GLOAD16(Abf + (size_t)(m0 + row) * K + k0 + col8, &As[(wave * 2 + q) * 512]);
            GLOAD16(Bt  + (size_t)(n0 + row) * K + k0 + col8, &Bs[(wave * 2 + q) * 512]);
        }
        __syncthreads();

        short8 a[4], b[4];
        #pragma unroll
        for (int mi = 0; mi < 4; ++mi)
            a[mi] = *(const short8*)&As[(wr * 64 + mi * 16 + c) * 32 + g * 8];
        #pragma unroll
        for (int ni = 0; ni < 4; ++ni)
            b[ni] = *(const short8*)&Bs[(wc * 64 + ni * 16 + c) * 32 + g * 8];
        #pragma unroll
        for (int mi = 0; mi < 4; ++mi)
            #pragma unroll
            for (int ni = 0; ni < 4; ++ni)
                acc[mi][ni] = __builtin_amdgcn_mfma_f32_16x16x32_bf16(a[mi], b[ni], acc[mi][ni], 0, 0, 0);
        __syncthreads();
    }

    #pragma unroll
    for (int mi = 0; mi < 4; ++mi) {
        int tbase = m0 + wr * 64 + mi * 16 + 4 * g;
        #pragma unroll
        for (int ni = 0; ni < 4; ++ni) {
            int n = n0 + wc * 64 + ni * 16 + c;
            float bv = bias[n];
            #pragma unroll
            for (int r = 0; r < 4; ++r)
                C[(size_t)(tbase + r) * D_MODEL + n] = acc[mi][ni][r] + bv;
        }
    }
}

extern "C" void kernel_launch(void* const* d_in, const int* in_sizes, int n_in,
                              void* d_out, int out_size, void* d_ws, size_t ws_size,
                              hipStream_t stream)
{
    const float* x    = (const float*)d_in[0];
    const float* rope = (const float*)d_in[1];
    const float* Wqkv = (const float*)d_in[2];
    const float* bqkv = (const float*)d_in[3];
    const float* Wo   = (const float*)d_in[4];
    const float* bo   = (const float*)d_in[5];
    float* out = (float*)d_out;
    float* ws  = (float*)d_ws;

    const size_t per2 = 2621440;   // one [H][T][80] bf16 buffer, in float units
    const size_t wt_f = 2457600;   // Wqkv_t bf16 in float units
    const size_t tab  = (size_t)T_LEN * HALF;

    ushort_t* qraw = (ushort_t*)ws;                 // attn_bf aliases after flash chain
    ushort_t* kraw = (ushort_t*)(ws + per2);        // dead after qk_prep -> lse
    ushort_t* vt   = (ushort_t*)(ws + 2 * per2);    // alive through flash
    ushort_t* xbf  = (ushort_t*)(ws + 3 * per2);    // dead after gemm1 -> po0
    ushort_t* Wt   = (ushort_t*)(ws + 4 * per2);    // dead after gemm1 -> po1 (spills into cs)
    float*    cs   = ws + 4 * per2 + wt_f;          // dead after qk_prep
    float*    sn   = cs + tab;                      // dead after qk_prep
    ushort_t* qbf  = (ushort_t*)(sn + tab);         // dead after flash
    ushort_t* kbf  = (ushort_t*)(sn + tab + per2);
    ushort_t* attn_bf = qraw;
    ushort_t* Wo_t = qbf;
    // flash partials (all in regions dead by flash launch time):
    float*    lse  = ws + per2;                     // 131072 floats (kraw region)
    ushort_t* po0  = xbf;                           // per2 float-slots, exact fit
    ushort_t* po1  = Wt;                            // wt_f + cs = 2621440 float-slots, exact

    rope_table<<<(T_LEN * HALF + 255) / 256, 256, 0, stream>>>(rope, cs, sn);

    cvt_bf16<<<(T_LEN * D_MODEL) / 1024, 256, 0, stream>>>(x, xbf);

    transpose_cvt<<<dim3(N_QKV / 64, D_MODEL / 64), 256, 0, stream>>>(Wqkv, Wt, D_MODEL, N_QKV);

    gemm_qkv_mfma<<<dim3(N_QKV / 128, T_LEN / 128), 256, 0, stream>>>(xbf, Wt, bqkv, qraw, kraw, vt);

    qk_prep<<<(H_NUM * T_LEN * HALF) / 256, 256, 0, stream>>>(qraw, kraw, cs, sn, qbf, kbf);

    flash_mfma<<<1024, 256, 0, stream>>>(qbf, kbf, vt, po0, po1, lse);

    merge_halves<<<2560, 256, 0, stream>>>(po0, po1, lse, attn_bf);

    transpose_cvt<<<dim3(D_MODEL / 64, D_MODEL / 64), 256, 0, stream>>>(Wo, Wo_t, D_MODEL, D_MODEL);

    gemm_out_mfma<<<dim3(D_MODEL / 128, T_LEN / 128), 256, 0, stream>>>(attn_bf, Wo_t, bo, out);
}

// Round 14
// 275.317 us; speedup vs baseline: 1.0575x; 1.0575x over previous
//
#include <hip/hip_runtime.h>
#include <math.h>

#define T_LEN 4096
#define D_MODEL 1280
#define H_NUM 16
#define HD 80
#define HALF 40
#define N_QKV (3*D_MODEL)

typedef short short8 __attribute__((ext_vector_type(8)));
typedef short short4v __attribute__((ext_vector_type(4)));
typedef float f32x4 __attribute__((ext_vector_type(4)));
typedef float f32x16 __attribute__((ext_vector_type(16)));
typedef float float4v __attribute__((ext_vector_type(4)));
typedef unsigned int uint4v __attribute__((ext_vector_type(4)));
typedef unsigned short ushort_t;

static __device__ __forceinline__ unsigned short f2bf(float f) {
    unsigned int u = __builtin_bit_cast(unsigned int, f);
    unsigned int r = (u + 0x7FFFu + ((u >> 16) & 1u)) >> 16;
    return (unsigned short)r;
}
static __device__ __forceinline__ float bf2f(unsigned short u) {
    return __builtin_bit_cast(float, (unsigned int)u << 16);
}

#define GLOAD16(gp, lp) \
    __builtin_amdgcn_global_load_lds((const __attribute__((address_space(1))) void*)(gp), \
                                     (__attribute__((address_space(3))) void*)(lp), 16, 0, 0)

// ---------------- rope tables ----------------
__global__ void rope_table(const float* __restrict__ rope,
                           float* __restrict__ cs, float* __restrict__ sn)
{
    int i = blockIdx.x * 256 + threadIdx.x;
    if (i < T_LEN * HALF) {
        float a = rope[i];
        cs[i] = cosf(a);
        sn[i] = sinf(a);
    }
}

// ---------------- fp32 -> bf16 elementwise (n % 1024 == 0) ----------------
__global__ __launch_bounds__(256) void cvt_bf16(const float* __restrict__ in,
                                                ushort_t* __restrict__ out)
{
    int i = (blockIdx.x * 256 + threadIdx.x) * 4;
    float4v v = *(const float4v*)&in[i];
    short4v o;
    o[0] = (short)f2bf(v[0]); o[1] = (short)f2bf(v[1]);
    o[2] = (short)f2bf(v[2]); o[3] = (short)f2bf(v[3]);
    *(short4v*)&out[i] = o;
}

// ---------------- fp32 [R][C] -> bf16 [C][R] transpose ----------------
__global__ __launch_bounds__(256) void transpose_cvt(const float* __restrict__ in,
                                                     ushort_t* __restrict__ out,
                                                     int R, int C)
{
    __shared__ float tile[64][65];
    int r0 = blockIdx.y * 64, c0 = blockIdx.x * 64;
    int tid = threadIdx.x;
    for (int i = tid; i < 4096; i += 256) {
        int r = i >> 6, c = i & 63;
        tile[r][c] = in[(size_t)(r0 + r) * C + c0 + c];
    }
    __syncthreads();
    for (int i = tid; i < 4096; i += 256) {
        int r = i >> 6, c = i & 63;
        out[(size_t)(c0 + r) * R + r0 + c] = f2bf(tile[c][r]);
    }
}

// ---------------- GEMM1 (bf16 MFMA, m97 structure): qkv = x @ Wqkv + b ----------------
__global__ __launch_bounds__(256) void gemm_qkv_mfma(const ushort_t* __restrict__ xbf,
                                                     const ushort_t* __restrict__ Wt,
                                                     const float* __restrict__ bias,
                                                     ushort_t* __restrict__ qraw,
                                                     ushort_t* __restrict__ kraw,
                                                     ushort_t* __restrict__ vt)
{
    __shared__ ushort_t As[128 * 32];
    __shared__ ushort_t Bs[128 * 32];
    const int tid = threadIdx.x;
    const int wave = tid >> 6, lane = tid & 63;
    const int g = lane >> 4, c = lane & 15;
    const int wr = wave >> 1, wc = wave & 1;
    const int m0 = blockIdx.y * 128, n0 = blockIdx.x * 128;
    const int K = D_MODEL;

    f32x4 acc[4][4];
    #pragma unroll
    for (int i = 0; i < 4; ++i)
        #pragma unroll
        for (int j = 0; j < 4; ++j) acc[i][j] = (f32x4)(0.f);

    for (int k0 = 0; k0 < K; k0 += 32) {
        #pragma unroll
        for (int q = 0; q < 2; ++q) {
            int j = wave * 128 + q * 64 + lane;
            int row = j >> 2, col8 = (j & 3) * 8;
            GLOAD16(xbf + (size_t)(m0 + row) * K + k0 + col8, &As[(wave * 2 + q) * 512]);
            GLOAD16(Wt  + (size_t)(n0 + row) * K + k0 + col8, &Bs[(wave * 2 + q) * 512]);
        }
        __syncthreads();

        short8 a[4], b[4];
        #pragma unroll
        for (int mi = 0; mi < 4; ++mi)
            a[mi] = *(const short8*)&As[(wr * 64 + mi * 16 + c) * 32 + g * 8];
        #pragma unroll
        for (int ni = 0; ni < 4; ++ni)
            b[ni] = *(const short8*)&Bs[(wc * 64 + ni * 16 + c) * 32 + g * 8];
        #pragma unroll
        for (int mi = 0; mi < 4; ++mi)
            #pragma unroll
            for (int ni = 0; ni < 4; ++ni)
                acc[mi][ni] = __builtin_amdgcn_mfma_f32_16x16x32_bf16(a[mi], b[ni], acc[mi][ni], 0, 0, 0);
        __syncthreads();
    }

    const int sel = n0 / D_MODEL;
    #pragma unroll
    for (int mi = 0; mi < 4; ++mi) {
        int tbase = m0 + wr * 64 + mi * 16 + 4 * g;
        #pragma unroll
        for (int ni = 0; ni < 4; ++ni) {
            int n = n0 + wc * 64 + ni * 16 + c;
            float bv = bias[n];
            int rem = n - sel * D_MODEL;
            int h = rem / HD, d = rem % HD;
            if (sel < 2) {
                ushort_t* dst = sel ? kraw : qraw;
                #pragma unroll
                for (int r = 0; r < 4; ++r)
                    dst[((size_t)h * T_LEN + tbase + r) * HD + d] = f2bf(acc[mi][ni][r] + bv);
            } else {
                short4v o;
                #pragma unroll
                for (int r = 0; r < 4; ++r) o[r] = (short)f2bf(acc[mi][ni][r] + bv);
                *(short4v*)&vt[((size_t)h * HD + d) * T_LEN + tbase] = o;
            }
        }
    }
}

// ---------------- rope on raw bf16 q,k; q gets scale*log2e folded in ----------------
__global__ __launch_bounds__(256) void qk_prep(const ushort_t* __restrict__ qraw,
                                               const ushort_t* __restrict__ kraw,
                                               const float* __restrict__ cs,
                                               const float* __restrict__ sn,
                                               ushort_t* __restrict__ qbf,
                                               ushort_t* __restrict__ kbf)
{
    const float SC = 0.16129842f;  // (1/sqrt(80)) * log2(e)
    int idx = blockIdx.x * 256 + threadIdx.x;
    int d = idx % HALF;
    int t = (idx / HALF) % T_LEN;
    int h = idx / (HALF * T_LEN);
    float c = cs[t * HALF + d], s = sn[t * HALF + d];
    size_t base = ((size_t)h * T_LEN + t) * HD;
    float qr = bf2f(qraw[base + d]), qi = bf2f(qraw[base + d + HALF]);
    qbf[base + d]        = f2bf((qr * c - qi * s) * SC);
    qbf[base + d + HALF] = f2bf((qr * s + qi * c) * SC);
    float kr = bf2f(kraw[base + d]), ki = bf2f(kraw[base + d + HALF]);
    kbf[base + d]        = f2bf(kr * c - ki * s);
    kbf[base + d + HALF] = f2bf(kr * s + ki * c);
}

// ---------------- Flash attention: 32x32x16 MFMA, global_load_lds 2-phase, KV-split ----
// Grid 1024 = 16 heads x 32 q-tiles x 2 kv-halves; 4 waves/block, 32 q-rows/wave.
// VGPR fix (m69): wave slots step at 64/128/256 VGPR; old kernel's 136 capped HW at
// 2 waves/SIMD (occupancy pinned 11% r8-r13). global_load_lds staging removes pf[5]
// (20 VGPRs) + all ds_writes -> VGPR<=128 target, __launch_bounds__(256,4) pins it.
// LDS chunk-major (gload_lds needs linear dests, m104): per 20 KB buffer,
//   K chunks [kc*64 + r] (kc<10, r<64): row r, k-span [kc*8, kc*8+8) ushorts
//   V chunks [640 + kvc*80 + f] (kvc<8, f<80): f-row f, kv-span [kvc*8, +8)
// Reads are consecutive-lane-16B -> bank-conflict-free. ft=2 PV rows clamped to
// 64+(ln&15): lanes 16-31 compute duplicate cols (finite, discarded at write).
// 2-phase loop: stage(next) -> compute(cur) -> __syncthreads (vmcnt drain = stage
// completion; loads in flight across entire compute phase — the m97 GEMM pattern).
// Swapped S^T = mfma(A=K, B=Q): lane holds S[kv=32*tau+crow(reg,hi)][q=ln],
//   crow(reg,hi) = (reg&3)+8*(reg>>2)+4*hi. PV A-frag via cvt_pk + permlane32_swap
//   pairs (X0,X2),(X1,X3),(X4,X6),(X5,X7)  [direction verified r7->r8].
__global__ __launch_bounds__(256, 4) void flash_mfma(const ushort_t* __restrict__ qbf,
                                                     const ushort_t* __restrict__ kbf,
                                                     const ushort_t* __restrict__ vt,
                                                     ushort_t* __restrict__ po0,
                                                     ushort_t* __restrict__ po1,
                                                     float* __restrict__ lse_g)
{
    // XCD swizzle (T1): XCD j = bid&7 serves heads {2j,2j+1}.
    const int bid = blockIdx.x;               // 1024 blocks
    const int h   = 2 * (bid & 7) + ((bid >> 3) >> 6);
    const int rem = (bid >> 3) & 63;
    const int kvh = rem & 1;
    const int q0  = (rem >> 1) * 128;
    const int kvbase = kvh * 32;              // 32 kv-tiles of 64 per half
    const int tid = threadIdx.x;
    const int wq = tid >> 6;
    const int lane = tid & 63;
    const int hi = lane >> 5;
    const int ln = lane & 31;

    // 2 buffers x 1280 chunks x 16B = 40 KB total
    __shared__ ushort_t lds[2][10240];

    // per-lane global chunk offsets (ushort units); group g = wq*5+u covers chunks [g*64, g*64+64)
    int goff[5];
    #pragma unroll
    for (int u = 0; u < 5; ++u) {
        int id = (wq * 5 + u) * 64 + lane;
        if (id < 640) { int kc = id >> 6, r = id & 63; goff[u] = r * HD + kc * 8; }
        else { int vid = id - 640; int kvc = vid / 80, f = vid - kvc * 80; goff[u] = f * T_LEN + kvc * 8; }
    }
    const ushort_t* gK = kbf + (size_t)h * T_LEN * HD;
    const ushort_t* gV = vt + (size_t)h * HD * T_LEN;

    // Q fragments (B-operand): col=ln, k = ch*16 + 8*hi + i  (K=80 exact, 5 chunks)
    short8 qf[5];
    {
        const ushort_t* qp = qbf + ((size_t)h * T_LEN + q0 + wq * 32 + ln) * HD + 8 * hi;
        #pragma unroll
        for (int ch = 0; ch < 5; ++ch) qf[ch] = *(const short8*)(qp + ch * 16);
    }

    f32x16 oacc[3];
    #pragma unroll
    for (int ft = 0; ft < 3; ++ft) oacc[ft] = (f32x16)(0.f);
    float m_run = -1e30f, l_run = 0.f;

    auto stage = [&](ushort_t* lbuf, int ktn) {   // ktn = GLOBAL kv-tile index
        const ushort_t* bK = gK + (size_t)ktn * 64 * HD;
        const ushort_t* bV = gV + ktn * 64;
        #pragma unroll
        for (int u = 0; u < 5; ++u) {
            int grp = wq * 5 + u;                 // wave-uniform
            const ushort_t* src = (grp < 10 ? bK : bV) + goff[u];
            GLOAD16(src, lbuf + grp * 512);       // dest: uniform base + lane*16 (HW)
        }
    };

    stage(&lds[0][0], kvbase);
    __syncthreads();                              // vmcnt drain: tile 0 visible

    for (int kt = 0; kt < 32; ++kt) {
        ushort_t* cur = &lds[kt & 1][0];
        stage(&lds[(kt & 1) ^ 1][0], kvbase + (kt < 31 ? kt + 1 : kt));  // in flight all iter

        // S^T: two 32x32 kv-tiles, K=80 in 5 chunks; K chunk kc = 2ch+hi
        f32x16 st0 = (f32x16)(0.f), st1 = (f32x16)(0.f);
        #pragma unroll
        for (int ch = 0; ch < 5; ++ch) {
            short8 a0 = *(const short8*)(cur + ((2 * ch + hi) * 64 + ln) * 8);
            st0 = __builtin_amdgcn_mfma_f32_32x32x16_bf16(a0, qf[ch], st0, 0, 0, 0);
        }
        #pragma unroll
        for (int ch = 0; ch < 5; ++ch) {
            short8 a1 = *(const short8*)(cur + ((2 * ch + hi) * 64 + 32 + ln) * 8);
            st1 = __builtin_amdgcn_mfma_f32_32x32x16_bf16(a1, qf[ch], st1, 0, 0, 0);
        }

        // row max: 32 in-lane + cross-half combine
        float mx = st0[0];
        #pragma unroll
        for (int i = 1; i < 16; ++i) mx = fmaxf(mx, st0[i]);
        #pragma unroll
        for (int i = 0; i < 16; ++i) mx = fmaxf(mx, st1[i]);
        mx = fmaxf(mx, __shfl_xor(mx, 32));

        // defer-max (exact): rescale only when max grew > 11 log2-units
        float al = 1.f;
        if (!__all(mx - m_run <= 11.0f)) {
            float m_new = fmaxf(m_run, mx);
            al = __builtin_amdgcn_exp2f(m_run - m_new);
            m_run = m_new;
            #pragma unroll
            for (int reg = 0; reg < 16; ++reg) {
                float alq = __shfl(al, (reg & 3) + 8 * (reg >> 2) + 4 * hi);
                oacc[0][reg] *= alq; oacc[1][reg] *= alq; oacc[2][reg] *= alq;
            }
        }

        float ps = 0.f;
        #pragma unroll
        for (int i = 0; i < 16; ++i) { st0[i] = __builtin_amdgcn_exp2f(st0[i] - m_run); ps += st0[i]; }
        #pragma unroll
        for (int i = 0; i < 16; ++i) { st1[i] = __builtin_amdgcn_exp2f(st1[i] - m_run); ps += st1[i]; }
        ps += __shfl_xor(ps, 32);
        l_run = l_run * al + ps;

        // P -> bf16 A-frags fully in-register (T12)
        unsigned int X[8], Y[8];
        #pragma unroll
        for (int k = 0; k < 8; ++k) {
            asm("v_cvt_pk_bf16_f32 %0, %1, %2" : "=v"(X[k]) : "v"(st0[2 * k]), "v"(st0[2 * k + 1]));
            asm("v_cvt_pk_bf16_f32 %0, %1, %2" : "=v"(Y[k]) : "v"(st1[2 * k]), "v"(st1[2 * k + 1]));
        }
        asm volatile("v_permlane32_swap_b32 %0, %1" : "+v"(X[0]), "+v"(X[2]));
        asm volatile("v_permlane32_swap_b32 %0, %1" : "+v"(X[1]), "+v"(X[3]));
        asm volatile("v_permlane32_swap_b32 %0, %1" : "+v"(X[4]), "+v"(X[6]));
        asm volatile("v_permlane32_swap_b32 %0, %1" : "+v"(X[5]), "+v"(X[7]));
        asm volatile("v_permlane32_swap_b32 %0, %1" : "+v"(Y[0]), "+v"(Y[2]));
        asm volatile("v_permlane32_swap_b32 %0, %1" : "+v"(Y[1]), "+v"(Y[3]));
        asm volatile("v_permlane32_swap_b32 %0, %1" : "+v"(Y[4]), "+v"(Y[6]));
        asm volatile("v_permlane32_swap_b32 %0, %1" : "+v"(Y[5]), "+v"(Y[7]));

        short8 pfrag[4];
        {
            uint4v u0 = {X[0], X[1], X[2], X[3]};
            uint4v u1 = {X[4], X[5], X[6], X[7]};
            uint4v u2 = {Y[0], Y[1], Y[2], Y[3]};
            uint4v u3 = {Y[4], Y[5], Y[6], Y[7]};
            pfrag[0] = __builtin_bit_cast(short8, u0);
            pfrag[1] = __builtin_bit_cast(short8, u1);
            pfrag[2] = __builtin_bit_cast(short8, u2);
            pfrag[3] = __builtin_bit_cast(short8, u3);
        }

        // O += P V : V chunk kvc = 2ch+hi; f-rows ln / 32+ln / 64+(ln&15) (clamped dup)
        #pragma unroll
        for (int ch = 0; ch < 4; ++ch) {
            int kvc = 2 * ch + hi;
            short8 b0 = *(const short8*)(cur + 5120 + (kvc * 80 + ln) * 8);
            oacc[0] = __builtin_amdgcn_mfma_f32_32x32x16_bf16(pfrag[ch], b0, oacc[0], 0, 0, 0);
            short8 b1 = *(const short8*)(cur + 5120 + (kvc * 80 + 32 + ln) * 8);
            oacc[1] = __builtin_amdgcn_mfma_f32_32x32x16_bf16(pfrag[ch], b1, oacc[1], 0, 0, 0);
            short8 b2 = *(const short8*)(cur + 5120 + (kvc * 80 + 64 + (ln & 15)) * 8);
            oacc[2] = __builtin_amdgcn_mfma_f32_32x32x16_bf16(pfrag[ch], b2, oacc[2], 0, 0, 0);
        }

        __syncthreads();   // drains vmcnt: next tile staged & visible; all cur reads done
    }

    // epilogue: partial out = O/l (bf16) + lse = m + log2(l) (fp32)
    ushort_t* po = kvh ? po1 : po0;
    float linv = 1.0f / l_run;
    float lse = m_run + __log2f(l_run);
    if (hi == 0)
        lse_g[(size_t)kvh * (H_NUM * T_LEN) + h * T_LEN + q0 + wq * 32 + ln] = lse;
    #pragma unroll
    for (int reg = 0; reg < 16; ++reg) {
        int q = (reg & 3) + 8 * (reg >> 2) + 4 * hi;
        float liq = __shfl(linv, q);
        size_t rb = (size_t)(q0 + wq * 32 + q) * D_MODEL + h * HD;
        po[rb + ln]      = f2bf(oacc[0][reg] * liq);
        po[rb + 32 + ln] = f2bf(oacc[1][reg] * liq);
        if (ln < 16)
            po[rb + 64 + ln] = f2bf(oacc[2][reg] * liq);
    }
}

// ---------------- merge the two kv-half partials (exact flash combine) ----------------
__global__ __launch_bounds__(256) void merge_halves(const ushort_t* __restrict__ po0,
                                                    const ushort_t* __restrict__ po1,
                                                    const float* __restrict__ lse_g,
                                                    ushort_t* __restrict__ outb)
{
    int i = (blockIdx.x * 256 + threadIdx.x) * 8;   // 5,242,880 elems / 8 -> grid 2560
    int t = i / D_MODEL, c = i % D_MODEL;
    int h = c / HD;
    float l0 = lse_g[h * T_LEN + t];
    float l1 = lse_g[H_NUM * T_LEN + h * T_LEN + t];
    float m = fmaxf(l0, l1);
    float w0 = __builtin_amdgcn_exp2f(l0 - m);
    float w1 = __builtin_amdgcn_exp2f(l1 - m);
    float inv = 1.0f / (w0 + w1);
    w0 *= inv; w1 *= inv;
    short8 a = *(const short8*)(po0 + i);
    short8 b = *(const short8*)(po1 + i);
    short8 o;
    #pragma unroll
    for (int j = 0; j < 8; ++j)
        o[j] = (short)f2bf(bf2f((unsigned short)a[j]) * w0 + bf2f((unsigned short)b[j]) * w1);
    *(short8*)(outb + i) = o;
}

// ---------------- GEMM2 (bf16 MFMA): out = attn @ Wo + bo, fp32 out ----------------
__global__ __launch_bounds__(256) void gemm_out_mfma(const ushort_t* __restrict__ Abf,
                                                     const ushort_t* __restrict__ Bt,
                                                     const float* __restrict__ bias,
                                                     float* __restrict__ C)
{
    __shared__ ushort_t As[128 * 32];
    __shared__ ushort_t Bs[128 * 32];
    const int tid = threadIdx.x;
    const int wave = tid >> 6, lane = tid & 63;
    const int g = lane >> 4, c = lane & 15;
    const int wr = wave >> 1, wc = wave & 1;
    const int m0 = blockIdx.y * 128, n0 = blockIdx.x * 128;
    const int K = D_MODEL;

    f32x4 acc[4][4];
    #pragma unroll
    for (int i = 0; i < 4; ++i)
        #pragma unroll
        for (int j = 0; j < 4; ++j) acc[i][j] = (f32x4)(0.f);

    for (int k0 = 0; k0 < K; k0 += 32) {
        #pragma unroll
        for (int q = 0; q < 2; ++q) {
            int j = wave * 128 + q * 64 + lane;
            int row = j >> 2, col8 = (j & 3) * 8;
            GLOAD16(Abf + (size_t)(m0 + row) * K + k0 + col8, &As[(wave * 2 + q) * 512]);
            GLOAD16(Bt  + (size_t)(n0 + row) * K + k0 + col8, &Bs[(wave * 2 + q) * 512]);
        }
        __syncthreads();

        short8 a[4], b[4];
        #pragma unroll
        for (int mi = 0; mi < 4; ++mi)
            a[mi] = *(const short8*)&As[(wr * 64 + mi * 16 + c) * 32 + g * 8];
        #pragma unroll
        for (int ni = 0; ni < 4; ++ni)
            b[ni] = *(const short8*)&Bs[(wc * 64 + ni * 16 + c) * 32 + g * 8];
        #pragma unroll
        for (int mi = 0; mi < 4; ++mi)
            #pragma unroll
            for (int ni = 0; ni < 4; ++ni)
                acc[mi][ni] = __builtin_amdgcn_mfma_f32_16x16x32_bf16(a[mi], b[ni], acc[mi][ni], 0, 0, 0);
        __syncthreads();
    }

    #pragma unroll
    for (int mi = 0; mi < 4; ++mi) {
        int tbase = m0 + wr * 64 + mi * 16 + 4 * g;
        #pragma unroll
        for (int ni = 0; ni < 4; ++ni) {
            int n = n0 + wc * 64 + ni * 16 + c;
            float bv = bias[n];
            #pragma unroll
            for (int r = 0; r < 4; ++r)
                C[(size_t)(tbase + r) * D_MODEL + n] = acc[mi][ni][r] + bv;
        }
    }
}

extern "C" void kernel_launch(void* const* d_in, const int* in_sizes, int n_in,
                              void* d_out, int out_size, void* d_ws, size_t ws_size,
                              hipStream_t stream)
{
    const float* x    = (const float*)d_in[0];
    const float* rope = (const float*)d_in[1];
    const float* Wqkv = (const float*)d_in[2];
    const float* bqkv = (const float*)d_in[3];
    const float* Wo   = (const float*)d_in[4];
    const float* bo   = (const float*)d_in[5];
    float* out = (float*)d_out;
    float* ws  = (float*)d_ws;

    const size_t per2 = 2621440;   // one [H][T][80] bf16 buffer, in float units
    const size_t wt_f = 2457600;   // Wqkv_t bf16 in float units
    const size_t tab  = (size_t)T_LEN * HALF;

    ushort_t* qraw = (ushort_t*)ws;                 // attn_bf aliases after flash chain
    ushort_t* kraw = (ushort_t*)(ws + per2);        // dead after qk_prep -> lse
    ushort_t* vt   = (ushort_t*)(ws + 2 * per2);    // alive through flash
    ushort_t* xbf  = (ushort_t*)(ws + 3 * per2);    // dead after gemm1 -> po0
    ushort_t* Wt   = (ushort_t*)(ws + 4 * per2);    // dead after gemm1 -> po1 (spills into cs)
    float*    cs   = ws + 4 * per2 + wt_f;          // dead after qk_prep
    float*    sn   = cs + tab;                      // dead after qk_prep
    ushort_t* qbf  = (ushort_t*)(sn + tab);         // dead after flash
    ushort_t* kbf  = (ushort_t*)(sn + tab + per2);
    ushort_t* attn_bf = qraw;
    ushort_t* Wo_t = qbf;
    // flash partials (all in regions dead by flash launch time):
    float*    lse  = ws + per2;                     // 131072 floats (kraw region)
    ushort_t* po0  = xbf;                           // per2 float-slots, exact fit
    ushort_t* po1  = Wt;                            // wt_f + cs = 2621440 float-slots, exact

    rope_table<<<(T_LEN * HALF + 255) / 256, 256, 0, stream>>>(rope, cs, sn);

    cvt_bf16<<<(T_LEN * D_MODEL) / 1024, 256, 0, stream>>>(x, xbf);

    transpose_cvt<<<dim3(N_QKV / 64, D_MODEL / 64), 256, 0, stream>>>(Wqkv, Wt, D_MODEL, N_QKV);

    gemm_qkv_mfma<<<dim3(N_QKV / 128, T_LEN / 128), 256, 0, stream>>>(xbf, Wt, bqkv, qraw, kraw, vt);

    qk_prep<<<(H_NUM * T_LEN * HALF) / 256, 256, 0, stream>>>(qraw, kraw, cs, sn, qbf, kbf);

    flash_mfma<<<1024, 256, 0, stream>>>(qbf, kbf, vt, po0, po1, lse);

    merge_halves<<<2560, 256, 0, stream>>>(po0, po1, lse, attn_bf);

    transpose_cvt<<<dim3(D_MODEL / 64, D_MODEL / 64), 256, 0, stream>>>(Wo, Wo_t, D_MODEL, D_MODEL);

    gemm_out_mfma<<<dim3(D_MODEL / 128, T_LEN / 128), 256, 0, stream>>>(attn_bf, Wo_t, bo, out);
}

// Round 16
// 268.784 us; speedup vs baseline: 1.0832x; 1.0243x over previous
//
#include <hip/hip_runtime.h>
#include <math.h>

#define T_LEN 4096
#define D_MODEL 1280
#define H_NUM 16
#define HD 80
#define HALF 40
#define N_QKV (3*D_MODEL)

typedef short short8 __attribute__((ext_vector_type(8)));
typedef short short4v __attribute__((ext_vector_type(4)));
typedef float f32x4 __attribute__((ext_vector_type(4)));
typedef float f32x16 __attribute__((ext_vector_type(16)));
typedef float float4v __attribute__((ext_vector_type(4)));
typedef unsigned int uint4v __attribute__((ext_vector_type(4)));
typedef unsigned short ushort_t;

static __device__ __forceinline__ unsigned short f2bf(float f) {
    unsigned int u = __builtin_bit_cast(unsigned int, f);
    unsigned int r = (u + 0x7FFFu + ((u >> 16) & 1u)) >> 16;
    return (unsigned short)r;
}
static __device__ __forceinline__ float bf2f(unsigned short u) {
    return __builtin_bit_cast(float, (unsigned int)u << 16);
}

#define GLOAD16(gp, lp) \
    __builtin_amdgcn_global_load_lds((const __attribute__((address_space(1))) void*)(gp), \
                                     (__attribute__((address_space(3))) void*)(lp), 16, 0, 0)

#define TILE_STRIDE 5120   // ushorts per (head,kv-tile) image: 10 chunks x 512

// ---------------- rope tables ----------------
__global__ void rope_table(const float* __restrict__ rope,
                           float* __restrict__ cs, float* __restrict__ sn)
{
    int i = blockIdx.x * 256 + threadIdx.x;
    if (i < T_LEN * HALF) {
        float a = rope[i];
        cs[i] = cosf(a);
        sn[i] = sinf(a);
    }
}

// ---------------- fp32 -> bf16 elementwise (n % 1024 == 0) ----------------
__global__ __launch_bounds__(256) void cvt_bf16(const float* __restrict__ in,
                                                ushort_t* __restrict__ out)
{
    int i = (blockIdx.x * 256 + threadIdx.x) * 4;
    float4v v = *(const float4v*)&in[i];
    short4v o;
    o[0] = (short)f2bf(v[0]); o[1] = (short)f2bf(v[1]);
    o[2] = (short)f2bf(v[2]); o[3] = (short)f2bf(v[3]);
    *(short4v*)&out[i] = o;
}

// ---------------- fp32 [R][C] -> bf16 [C][R] transpose ----------------
__global__ __launch_bounds__(256) void transpose_cvt(const float* __restrict__ in,
                                                     ushort_t* __restrict__ out,
                                                     int R, int C)
{
    __shared__ float tile[64][65];
    int r0 = blockIdx.y * 64, c0 = blockIdx.x * 64;
    int tid = threadIdx.x;
    for (int i = tid; i < 4096; i += 256) {
        int r = i >> 6, c = i & 63;
        tile[r][c] = in[(size_t)(r0 + r) * C + c0 + c];
    }
    __syncthreads();
    for (int i = tid; i < 4096; i += 256) {
        int r = i >> 6, c = i & 63;
        out[(size_t)(c0 + r) * R + r0 + c] = f2bf(tile[c][r]);
    }
}

// ---------------- GEMM1 (bf16 MFMA, m97 structure): qkv = x @ Wqkv + b ----------------
// V epilogue writes the flash V-TILE IMAGE: vimg[(h*64+kt)*5120 + ((rr>>3)*80 + d)*8 + (rr&7)]
// (kt = t/64, rr = t%64). Each (h,kt) V-image = 10KB contiguous, byte-identical to
// flash's LDS V half -> staging is linear 1KB coalesced copies.
__global__ __launch_bounds__(256) void gemm_qkv_mfma(const ushort_t* __restrict__ xbf,
                                                     const ushort_t* __restrict__ Wt,
                                                     const float* __restrict__ bias,
                                                     ushort_t* __restrict__ qraw,
                                                     ushort_t* __restrict__ kraw,
                                                     ushort_t* __restrict__ vimg)
{
    __shared__ ushort_t As[128 * 32];
    __shared__ ushort_t Bs[128 * 32];
    const int tid = threadIdx.x;
    const int wave = tid >> 6, lane = tid & 63;
    const int g = lane >> 4, c = lane & 15;
    const int wr = wave >> 1, wc = wave & 1;
    const int m0 = blockIdx.y * 128, n0 = blockIdx.x * 128;
    const int K = D_MODEL;

    f32x4 acc[4][4];
    #pragma unroll
    for (int i = 0; i < 4; ++i)
        #pragma unroll
        for (int j = 0; j < 4; ++j) acc[i][j] = (f32x4)(0.f);

    for (int k0 = 0; k0 < K; k0 += 32) {
        #pragma unroll
        for (int q = 0; q < 2; ++q) {
            int j = wave * 128 + q * 64 + lane;
            int row = j >> 2, col8 = (j & 3) * 8;
            GLOAD16(xbf + (size_t)(m0 + row) * K + k0 + col8, &As[(wave * 2 + q) * 512]);
            GLOAD16(Wt  + (size_t)(n0 + row) * K + k0 + col8, &Bs[(wave * 2 + q) * 512]);
        }
        __syncthreads();

        short8 a[4], b[4];
        #pragma unroll
        for (int mi = 0; mi < 4; ++mi)
            a[mi] = *(const short8*)&As[(wr * 64 + mi * 16 + c) * 32 + g * 8];
        #pragma unroll
        for (int ni = 0; ni < 4; ++ni)
            b[ni] = *(const short8*)&Bs[(wc * 64 + ni * 16 + c) * 32 + g * 8];
        #pragma unroll
        for (int mi = 0; mi < 4; ++mi)
            #pragma unroll
            for (int ni = 0; ni < 4; ++ni)
                acc[mi][ni] = __builtin_amdgcn_mfma_f32_16x16x32_bf16(a[mi], b[ni], acc[mi][ni], 0, 0, 0);
        __syncthreads();
    }

    const int sel = n0 / D_MODEL;
    #pragma unroll
    for (int mi = 0; mi < 4; ++mi) {
        int tbase = m0 + wr * 64 + mi * 16 + 4 * g;
        #pragma unroll
        for (int ni = 0; ni < 4; ++ni) {
            int n = n0 + wc * 64 + ni * 16 + c;
            float bv = bias[n];
            int rem = n - sel * D_MODEL;
            int h = rem / HD, d = rem % HD;
            if (sel < 2) {
                ushort_t* dst = sel ? kraw : qraw;
                #pragma unroll
                for (int r = 0; r < 4; ++r)
                    dst[((size_t)h * T_LEN + tbase + r) * HD + d] = f2bf(acc[mi][ni][r] + bv);
            } else {
                short4v o;
                #pragma unroll
                for (int r = 0; r < 4; ++r) o[r] = (short)f2bf(acc[mi][ni][r] + bv);
                int kt = tbase >> 6, rr = tbase & 63;      // rr%8 in {0,4}: 4 consecutive kvp
                *(short4v*)&vimg[((size_t)(h * 64 + kt)) * TILE_STRIDE + ((rr >> 3) * 80 + d) * 8 + (rr & 7)] = o;
            }
        }
    }
}

// ---------------- rope on raw bf16 q,k; q gets scale*log2e folded in ----------------
// K output is the flash K-TILE IMAGE: kimg[(h*64+kt)*5120 + ((d>>3)*64 + r)*8 + (d&7)]
// (kt = t/64, r = t%64) -> per-tile 10KB contiguous = LDS K half.
__global__ __launch_bounds__(256) void qk_prep(const ushort_t* __restrict__ qraw,
                                               const ushort_t* __restrict__ kraw,
                                               const float* __restrict__ cs,
                                               const float* __restrict__ sn,
                                               ushort_t* __restrict__ qbf,
                                               ushort_t* __restrict__ kimg)
{
    const float SC = 0.16129842f;  // (1/sqrt(80)) * log2(e)
    int idx = blockIdx.x * 256 + threadIdx.x;
    int d = idx % HALF;
    int t = (idx / HALF) % T_LEN;
    int h = idx / (HALF * T_LEN);
    float c = cs[t * HALF + d], s = sn[t * HALF + d];
    size_t base = ((size_t)h * T_LEN + t) * HD;
    float qr = bf2f(qraw[base + d]), qi = bf2f(qraw[base + d + HALF]);
    qbf[base + d]        = f2bf((qr * c - qi * s) * SC);
    qbf[base + d + HALF] = f2bf((qr * s + qi * c) * SC);
    float kr = bf2f(kraw[base + d]), ki = bf2f(kraw[base + d + HALF]);
    size_t tb = ((size_t)(h * 64 + (t >> 6))) * TILE_STRIDE;
    int r = t & 63;
    int d2 = d + HALF;                       // d2%8 == d%8 (40%8==0)
    kimg[tb + ((d  >> 3) * 64 + r) * 8 + (d & 7)] = f2bf(kr * c - ki * s);
    kimg[tb + ((d2 >> 3) * 64 + r) * 8 + (d & 7)] = f2bf(kr * s + ki * c);
}

// ---------------- Flash attention: 32x32x16 MFMA, image-staged gload_lds, KV-split ----
// Grid 1024 = 16 heads x 32 q-tiles x 2 kv-halves; 4 waves/block, 32 q-rows/wave.
// r14 kept: VGPR 64 (4 waves/SIMD), chunk-major LDS (0 bank conflicts), 40KB dbuf
// (4 blocks/CU), 2-phase loop. r16 fix vs r15: tile image stride = 5120 ushorts
// (each K or V tile image is 10 chunks x 512 = 10KB; r15's 10240 stride doubled the
// buffers and overlapped vimg with xbf/po0 -> corrupted inputs, 0.226 error).
// LDS per buffer: K chunks (kc<10) at [(kc*64+r)*8]; V chunks (kvc<8) at 5120 +
// [(kvc*80+f)*8]. Staging: 20 linear 1KB copies, lane-consecutive src (coalesced).
// Swapped S^T = mfma(A=K, B=Q): lane holds S[kv=32*tau+crow(reg,hi)][q=ln],
//   crow(reg,hi) = (reg&3)+8*(reg>>2)+4*hi. PV A-frag via cvt_pk + permlane32_swap
//   pairs (X0,X2),(X1,X3),(X4,X6),(X5,X7)  [direction verified r7->r8].
__global__ __launch_bounds__(256, 4) void flash_mfma(const ushort_t* __restrict__ qbf,
                                                     const ushort_t* __restrict__ kimg,
                                                     const ushort_t* __restrict__ vimg,
                                                     ushort_t* __restrict__ po0,
                                                     ushort_t* __restrict__ po1,
                                                     float* __restrict__ lse_g)
{
    // XCD swizzle (T1): XCD j = bid&7 serves heads {2j,2j+1}.
    const int bid = blockIdx.x;               // 1024 blocks
    const int h   = 2 * (bid & 7) + ((bid >> 3) >> 6);
    const int rem = (bid >> 3) & 63;
    const int kvh = rem & 1;
    const int q0  = (rem >> 1) * 128;
    const int kvbase = kvh * 32;              // 32 kv-tiles of 64 per half
    const int tid = threadIdx.x;
    const int wq = tid >> 6;
    const int lane = tid & 63;
    const int hi = lane >> 5;
    const int ln = lane & 31;

    // 2 buffers x 10240 ushorts (20 KB) = 40 KB total
    __shared__ ushort_t lds[2][10240];

    const ushort_t* kh = kimg + ((size_t)h * 64) * TILE_STRIDE;
    const ushort_t* vh = vimg + ((size_t)h * 64) * TILE_STRIDE;

    // Q fragments (B-operand): col=ln, k = ch*16 + 8*hi + i  (K=80 exact, 5 chunks)
    short8 qf[5];
    {
        const ushort_t* qp = qbf + ((size_t)h * T_LEN + q0 + wq * 32 + ln) * HD + 8 * hi;
        #pragma unroll
        for (int ch = 0; ch < 5; ++ch) qf[ch] = *(const short8*)(qp + ch * 16);
    }

    f32x16 oacc[3];
    #pragma unroll
    for (int ft = 0; ft < 3; ++ft) oacc[ft] = (f32x16)(0.f);
    float m_run = -1e30f, l_run = 0.f;

    auto stage = [&](ushort_t* lbuf, int ktn) {   // ktn = GLOBAL kv-tile index
        const ushort_t* kt_img = kh + (size_t)ktn * TILE_STRIDE;
        const ushort_t* vt_img = vh + (size_t)ktn * TILE_STRIDE;
        #pragma unroll
        for (int u = 0; u < 5; ++u) {
            int grp = wq * 5 + u;                 // wave-uniform group id, 20 groups
            const ushort_t* src = (grp < 10 ? kt_img + grp * 512
                                            : vt_img + (grp - 10) * 512) + lane * 8;
            GLOAD16(src, lbuf + grp * 512);       // linear 1KB copy, lane-consecutive src
        }
    };

    stage(&lds[0][0], kvbase);
    __syncthreads();                              // vmcnt drain: tile 0 visible

    for (int kt = 0; kt < 32; ++kt) {
        ushort_t* cur = &lds[kt & 1][0];
        stage(&lds[(kt & 1) ^ 1][0], kvbase + (kt < 31 ? kt + 1 : kt));  // in flight all iter

        // S^T: two 32x32 kv-tiles, K=80 in 5 chunks; K chunk kc = 2ch+hi
        f32x16 st0 = (f32x16)(0.f), st1 = (f32x16)(0.f);
        #pragma unroll
        for (int ch = 0; ch < 5; ++ch) {
            short8 a0 = *(const short8*)(cur + ((2 * ch + hi) * 64 + ln) * 8);
            st0 = __builtin_amdgcn_mfma_f32_32x32x16_bf16(a0, qf[ch], st0, 0, 0, 0);
        }
        #pragma unroll
        for (int ch = 0; ch < 5; ++ch) {
            short8 a1 = *(const short8*)(cur + ((2 * ch + hi) * 64 + 32 + ln) * 8);
            st1 = __builtin_amdgcn_mfma_f32_32x32x16_bf16(a1, qf[ch], st1, 0, 0, 0);
        }

        // row max: 32 in-lane + cross-half combine
        float mx = st0[0];
        #pragma unroll
        for (int i = 1; i < 16; ++i) mx = fmaxf(mx, st0[i]);
        #pragma unroll
        for (int i = 0; i < 16; ++i) mx = fmaxf(mx, st1[i]);
        mx = fmaxf(mx, __shfl_xor(mx, 32));

        // defer-max (exact): rescale only when max grew > 11 log2-units
        float al = 1.f;
        if (!__all(mx - m_run <= 11.0f)) {
            float m_new = fmaxf(m_run, mx);
            al = __builtin_amdgcn_exp2f(m_run - m_new);
            m_run = m_new;
            #pragma unroll
            for (int reg = 0; reg < 16; ++reg) {
                float alq = __shfl(al, (reg & 3) + 8 * (reg >> 2) + 4 * hi);
                oacc[0][reg] *= alq; oacc[1][reg] *= alq; oacc[2][reg] *= alq;
            }
        }

        float ps = 0.f;
        #pragma unroll
        for (int i = 0; i < 16; ++i) { st0[i] = __builtin_amdgcn_exp2f(st0[i] - m_run); ps += st0[i]; }
        #pragma unroll
        for (int i = 0; i < 16; ++i) { st1[i] = __builtin_amdgcn_exp2f(st1[i] - m_run); ps += st1[i]; }
        ps += __shfl_xor(ps, 32);
        l_run = l_run * al + ps;

        // P -> bf16 A-frags fully in-register (T12)
        unsigned int X[8], Y[8];
        #pragma unroll
        for (int k = 0; k < 8; ++k) {
            asm("v_cvt_pk_bf16_f32 %0, %1, %2" : "=v"(X[k]) : "v"(st0[2 * k]), "v"(st0[2 * k + 1]));
            asm("v_cvt_pk_bf16_f32 %0, %1, %2" : "=v"(Y[k]) : "v"(st1[2 * k]), "v"(st1[2 * k + 1]));
        }
        asm volatile("v_permlane32_swap_b32 %0, %1" : "+v"(X[0]), "+v"(X[2]));
        asm volatile("v_permlane32_swap_b32 %0, %1" : "+v"(X[1]), "+v"(X[3]));
        asm volatile("v_permlane32_swap_b32 %0, %1" : "+v"(X[4]), "+v"(X[6]));
        asm volatile("v_permlane32_swap_b32 %0, %1" : "+v"(X[5]), "+v"(X[7]));
        asm volatile("v_permlane32_swap_b32 %0, %1" : "+v"(Y[0]), "+v"(Y[2]));
        asm volatile("v_permlane32_swap_b32 %0, %1" : "+v"(Y[1]), "+v"(Y[3]));
        asm volatile("v_permlane32_swap_b32 %0, %1" : "+v"(Y[4]), "+v"(Y[6]));
        asm volatile("v_permlane32_swap_b32 %0, %1" : "+v"(Y[5]), "+v"(Y[7]));

        short8 pfrag[4];
        {
            uint4v u0 = {X[0], X[1], X[2], X[3]};
            uint4v u1 = {X[4], X[5], X[6], X[7]};
            uint4v u2 = {Y[0], Y[1], Y[2], Y[3]};
            uint4v u3 = {Y[4], Y[5], Y[6], Y[7]};
            pfrag[0] = __builtin_bit_cast(short8, u0);
            pfrag[1] = __builtin_bit_cast(short8, u1);
            pfrag[2] = __builtin_bit_cast(short8, u2);
            pfrag[3] = __builtin_bit_cast(short8, u3);
        }

        // O += P V : V chunk kvc = 2ch+hi; f-rows ln / 32+ln / 64+(ln&15) (clamped dup)
        #pragma unroll
        for (int ch = 0; ch < 4; ++ch) {
            int kvc = 2 * ch + hi;
            short8 b0 = *(const short8*)(cur + 5120 + (kvc * 80 + ln) * 8);
            oacc[0] = __builtin_amdgcn_mfma_f32_32x32x16_bf16(pfrag[ch], b0, oacc[0], 0, 0, 0);
            short8 b1 = *(const short8*)(cur + 5120 + (kvc * 80 + 32 + ln) * 8);
            oacc[1] = __builtin_amdgcn_mfma_f32_32x32x16_bf16(pfrag[ch], b1, oacc[1], 0, 0, 0);
            short8 b2 = *(const short8*)(cur + 5120 + (kvc * 80 + 64 + (ln & 15)) * 8);
            oacc[2] = __builtin_amdgcn_mfma_f32_32x32x16_bf16(pfrag[ch], b2, oacc[2], 0, 0, 0);
        }

        __syncthreads();   // drains vmcnt: next tile staged & visible; all cur reads done
    }

    // epilogue: partial out = O/l (bf16) + lse = m + log2(l) (fp32)
    ushort_t* po = kvh ? po1 : po0;
    float linv = 1.0f / l_run;
    float lse = m_run + __log2f(l_run);
    if (hi == 0)
        lse_g[(size_t)kvh * (H_NUM * T_LEN) + h * T_LEN + q0 + wq * 32 + ln] = lse;
    #pragma unroll
    for (int reg = 0; reg < 16; ++reg) {
        int q = (reg & 3) + 8 * (reg >> 2) + 4 * hi;
        float liq = __shfl(linv, q);
        size_t rb = (size_t)(q0 + wq * 32 + q) * D_MODEL + h * HD;
        po[rb + ln]      = f2bf(oacc[0][reg] * liq);
        po[rb + 32 + ln] = f2bf(oacc[1][reg] * liq);
        if (ln < 16)
            po[rb + 64 + ln] = f2bf(oacc[2][reg] * liq);
    }
}

// ---------------- merge the two kv-half partials (exact flash combine) ----------------
__global__ __launch_bounds__(256) void merge_halves(const ushort_t* __restrict__ po0,
                                                    const ushort_t* __restrict__ po1,
                                                    const float* __restrict__ lse_g,
                                                    ushort_t* __restrict__ outb)
{
    int i = (blockIdx.x * 256 + threadIdx.x) * 8;   // 5,242,880 elems / 8 -> grid 2560
    int t = i / D_MODEL, c = i % D_MODEL;
    int h = c / HD;
    float l0 = lse_g[h * T_LEN + t];
    float l1 = lse_g[H_NUM * T_LEN + h * T_LEN + t];
    float m = fmaxf(l0, l1);
    float w0 = __builtin_amdgcn_exp2f(l0 - m);
    float w1 = __builtin_amdgcn_exp2f(l1 - m);
    float inv = 1.0f / (w0 + w1);
    w0 *= inv; w1 *= inv;
    short8 a = *(const short8*)(po0 + i);
    short8 b = *(const short8*)(po1 + i);
    short8 o;
    #pragma unroll
    for (int j = 0; j < 8; ++j)
        o[j] = (short)f2bf(bf2f((unsigned short)a[j]) * w0 + bf2f((unsigned short)b[j]) * w1);
    *(short8*)(outb + i) = o;
}

// ---------------- GEMM2 (bf16 MFMA): out = attn @ Wo + bo, fp32 out ----------------
__global__ __launch_bounds__(256) void gemm_out_mfma(const ushort_t* __restrict__ Abf,
                                                     const ushort_t* __restrict__ Bt,
                                                     const float* __restrict__ bias,
                                                     float* __restrict__ C)
{
    __shared__ ushort_t As[128 * 32];
    __shared__ ushort_t Bs[128 * 32];
    const int tid = threadIdx.x;
    const int wave = tid >> 6, lane = tid & 63;
    const int g = lane >> 4, c = lane & 15;
    const int wr = wave >> 1, wc = wave & 1;
    const int m0 = blockIdx.y * 128, n0 = blockIdx.x * 128;
    const int K = D_MODEL;

    f32x4 acc[4][4];
    #pragma unroll
    for (int i = 0; i < 4; ++i)
        #pragma unroll
        for (int j = 0; j < 4; ++j) acc[i][j] = (f32x4)(0.f);

    for (int k0 = 0; k0 < K; k0 += 32) {
        #pragma unroll
        for (int q = 0; q < 2; ++q) {
            int j = wave * 128 + q * 64 + lane;
            int row = j >> 2, col8 = (j & 3) * 8;
            GLOAD16(Abf + (size_t)(m0 + row) * K + k0 + col8, &As[(wave * 2 + q) * 512]);
            GLOAD16(Bt  + (size_t)(n0 + row) * K + k0 + col8, &Bs[(wave * 2 + q) * 512]);
        }
        __syncthreads();

        short8 a[4], b[4];
        #pragma unroll
        for (int mi = 0; mi < 4; ++mi)
            a[mi] = *(const short8*)&As[(wr * 64 + mi * 16 + c) * 32 + g * 8];
        #pragma unroll
        for (int ni = 0; ni < 4; ++ni)
            b[ni] = *(const short8*)&Bs[(wc * 64 + ni * 16 + c) * 32 + g * 8];
        #pragma unroll
        for (int mi = 0; mi < 4; ++mi)
            #pragma unroll
            for (int ni = 0; ni < 4; ++ni)
                acc[mi][ni] = __builtin_amdgcn_mfma_f32_16x16x32_bf16(a[mi], b[ni], acc[mi][ni], 0, 0, 0);
        __syncthreads();
    }

    #pragma unroll
    for (int mi = 0; mi < 4; ++mi) {
        int tbase = m0 + wr * 64 + mi * 16 + 4 * g;
        #pragma unroll
        for (int ni = 0; ni < 4; ++ni) {
            int n = n0 + wc * 64 + ni * 16 + c;
            float bv = bias[n];
            #pragma unroll
            for (int r = 0; r < 4; ++r)
                C[(size_t)(tbase + r) * D_MODEL + n] = acc[mi][ni][r] + bv;
        }
    }
}

extern "C" void kernel_launch(void* const* d_in, const int* in_sizes, int n_in,
                              void* d_out, int out_size, void* d_ws, size_t ws_size,
                              hipStream_t stream)
{
    const float* x    = (const float*)d_in[0];
    const float* rope = (const float*)d_in[1];
    const float* Wqkv = (const float*)d_in[2];
    const float* bqkv = (const float*)d_in[3];
    const float* Wo   = (const float*)d_in[4];
    const float* bo   = (const float*)d_in[5];
    float* out = (float*)d_out;
    float* ws  = (float*)d_ws;

    const size_t per2 = 2621440;   // one [H][T][80]-sized bf16 buffer, in float units
    const size_t wt_f = 2457600;   // Wqkv_t bf16 in float units
    const size_t tab  = (size_t)T_LEN * HALF;

    ushort_t* qraw = (ushort_t*)ws;                 // attn_bf aliases after flash chain
    ushort_t* kraw = (ushort_t*)(ws + per2);        // dead after qk_prep -> lse
    ushort_t* vimg = (ushort_t*)(ws + 2 * per2);    // V tile-image (per2 slots), alive thru flash
    ushort_t* xbf  = (ushort_t*)(ws + 3 * per2);    // dead after gemm1 -> po0
    ushort_t* Wt   = (ushort_t*)(ws + 4 * per2);    // dead after gemm1 -> po1 (spills into cs)
    float*    cs   = ws + 4 * per2 + wt_f;          // dead after qk_prep
    float*    sn   = cs + tab;                      // dead after qk_prep
    ushort_t* qbf  = (ushort_t*)(sn + tab);         // dead after flash
    ushort_t* kimg = (ushort_t*)(sn + tab + per2);  // K tile-image (per2 slots)
    ushort_t* attn_bf = qraw;
    ushort_t* Wo_t = qbf;
    // flash partials (all in regions dead by flash launch time):
    float*    lse  = ws + per2;                     // 131072 floats (kraw region)
    ushort_t* po0  = xbf;                           // per2 float-slots, exact fit
    ushort_t* po1  = Wt;                            // wt_f + cs = 2621440 float-slots, exact

    rope_table<<<(T_LEN * HALF + 255) / 256, 256, 0, stream>>>(rope, cs, sn);

    cvt_bf16<<<(T_LEN * D_MODEL) / 1024, 256, 0, stream>>>(x, xbf);

    transpose_cvt<<<dim3(N_QKV / 64, D_MODEL / 64), 256, 0, stream>>>(Wqkv, Wt, D_MODEL, N_QKV);

    gemm_qkv_mfma<<<dim3(N_QKV / 128, T_LEN / 128), 256, 0, stream>>>(xbf, Wt, bqkv, qraw, kraw, vimg);

    qk_prep<<<(H_NUM * T_LEN * HALF) / 256, 256, 0, stream>>>(qraw, kraw, cs, sn, qbf, kimg);

    flash_mfma<<<1024, 256, 0, stream>>>(qbf, kimg, vimg, po0, po1, lse);

    merge_halves<<<2560, 256, 0, stream>>>(po0, po1, lse, attn_bf);

    transpose_cvt<<<dim3(D_MODEL / 64, D_MODEL / 64), 256, 0, stream>>>(Wo, Wo_t, D_MODEL, D_MODEL);

    gemm_out_mfma<<<dim3(D_MODEL / 128, T_LEN / 128), 256, 0, stream>>>(attn_bf, Wo_t, bo, out);
}